// Round 4
// baseline (2342.390 us; speedup 1.0000x reference)
//
#include <hip/hip_runtime.h>
#include <hip/hip_bf16.h>
#include <cstddef>

#define HD 512

typedef short s8v __attribute__((ext_vector_type(8)));
typedef short s4v __attribute__((ext_vector_type(4)));
typedef float fx4 __attribute__((ext_vector_type(4)));

#define MFMA(a, b, c) __builtin_amdgcn_mfma_f32_16x16x32_bf16((a), (b), (c), 0, 0, 0)

__device__ __forceinline__ unsigned short f2bf(float f) {
  unsigned int u = __float_as_uint(f);
  unsigned int r = (u + 0x7fffu + ((u >> 16) & 1u)) >> 16;
  return (unsigned short)r;
}
__device__ __forceinline__ float bf2f(unsigned short u) {
  return __uint_as_float(((unsigned int)u) << 16);
}

// Swizzled B-operand layout for 16x16x32 MFMA (R1/R3-proven):
// element (k,n) -> chunk (ntile*KT + kt); lane = ((k&31)>>3)<<4 | (n&15); i = k&7
__device__ __forceinline__ size_t swz_off(int k, int n, int KT) {
  int kt = k >> 5, kr = k & 31;
  int nt = n >> 4, nr = n & 15;
  int lane = ((kr >> 3) << 4) | nr;
  int i = kr & 7;
  return ((((size_t)nt * KT + kt) * 64 + lane) << 3) + i;
}

// ---------------- pack weights ----------------
// W1 = [w_r | wz_top | wh_top] (512x1536, KT=16); WZB/WHB/WUR 512x512 KT=16; WO 1024x512 KT=32
__global__ void pack_kernel(const float* w_r, const float* ur, const float* wz, const float* wh,
                            const float* wo,
                            unsigned short* W1, unsigned short* WZB, unsigned short* WHB,
                            unsigned short* WUR, unsigned short* WO) {
  int idx = blockIdx.x * blockDim.x + threadIdx.x;
  int stride = gridDim.x * blockDim.x;
  for (int t = idx; t < 512 * 1536; t += stride) {
    int k = t / 1536, n = t - k * 1536;
    float v;
    if (n < 512) v = w_r[k * 512 + n];
    else if (n < 1024) v = wz[k * 512 + (n - 512)];
    else v = wh[k * 512 + (n - 1024)];
    W1[swz_off(k, n, 16)] = f2bf(v);
  }
  for (int t = idx; t < 512 * 512; t += stride) {
    int k = t >> 9, n = t & 511;
    size_t o = swz_off(k, n, 16);
    WZB[o] = f2bf(wz[(512 + k) * 512 + n]);
    WHB[o] = f2bf(wh[(512 + k) * 512 + n]);
    WUR[o] = f2bf(ur[k * 512 + n]);
  }
  for (int t = idx; t < 1024 * 512; t += stride) {
    int k = t >> 9, n = t & 511;
    WO[swz_off(k, n, 32)] = f2bf(wo[k * 512 + n]);
  }
}

// ---------------- embedding gather ----------------
__global__ void embed_kernel(const int* wid, const float* emb, unsigned short* x_bf, int BN) {
  int idx = blockIdx.x * blockDim.x + threadIdx.x;
  int stride = gridDim.x * blockDim.x;
  int total = BN * (HD / 8);
  for (int t = idx; t < total; t += stride) {
    int nrow = t >> 6;
    int c8 = (t & 63) << 3;
    int w = wid[nrow];
    const float4* s = (const float4*)(emb + (size_t)w * HD + c8);
    float4 v0 = s[0], v1 = s[1];
    s8v o;
    o[0] = (short)f2bf(v0.x); o[1] = (short)f2bf(v0.y);
    o[2] = (short)f2bf(v0.z); o[3] = (short)f2bf(v0.w);
    o[4] = (short)f2bf(v1.x); o[5] = (short)f2bf(v1.y);
    o[6] = (short)f2bf(v1.z); o[7] = (short)f2bf(v1.w);
    *(s8v*)&x_bf[(size_t)nrow * HD + c8] = o;
  }
}

// ---------------- schedule ----------------
__global__ void schedule_kernel(const int* preds, int E, int Epc, int P, int* sched) {
  __shared__ int rnd[64];
  int t = threadIdx.x;
  rnd[t] = -1;
  __syncthreads();
  for (int it = 0; it <= Epc; ++it) {
    int newv = -1;
    if (t < Epc && rnd[t] < 0) {
      int mx = 0;
      bool ready = true;
      for (int q = 0; q < P; ++q) {
        int pe = preds[t * P + q];
        if (pe < E) {
          int rp = rnd[pe];
          if (rp < 0) ready = false;
          else if (rp + 1 > mx) mx = rp + 1;
        }
      }
      if (ready) newv = mx;
    }
    __syncthreads();
    if (newv >= 0) rnd[t] = newv;
    __syncthreads();
  }
  if (t == 0) {
    int R = 0;
    for (int e = 0; e < Epc; ++e) if (rnd[e] + 1 > R) R = rnd[e] + 1;
    if (R > 31) R = 31;
    sched[0] = R;
    for (int r = 0; r < 31; ++r) {
      int c = 0;
      if (r < R) {
        for (int e = 0; e < Epc; ++e) if (rnd[e] == r) { sched[33 + r * 32 + c] = e; ++c; }
      }
      sched[1 + r] = c;
    }
  }
}

// ---------------- XP = x_bf @ W1 (32768 x 1536, K=512) ----------------
// 32-row x 512-col blocks; slab = which 512-col third; dbuf staging, 1 sync/kt, 16 MFMA/wave/kt
__global__ __launch_bounds__(256) void gemm_pre_kernel(const unsigned short* x_bf,
                                                       const unsigned short* W1,
                                                       unsigned short* XP, int BN) {
  __shared__ unsigned short lA[2][32 * 40];
  const int nM = BN >> 5;
  const int slab = blockIdx.x / nM;
  const int mt = blockIdx.x - slab * nM;
  const int tid = threadIdx.x, lane = tid & 63, w = tid >> 6;
  const int wm = w & 1, wn = w >> 1;
  const int m0 = mt << 5;
  const int srow = tid >> 3, sq4 = (tid & 7) << 2;
  const int arow = (wm << 4) | (lane & 15), k8 = (lane >> 4) << 3;
  fx4 ac[16];
#pragma unroll
  for (int i = 0; i < 16; i++) { ac[i][0]=0.f; ac[i][1]=0.f; ac[i][2]=0.f; ac[i][3]=0.f; }
  const unsigned short* aptr = x_bf + (size_t)(m0 + srow) * 512 + sq4;
  *(s4v*)&lA[0][srow * 40 + sq4] = *(const s4v*)aptr;
  for (int kt = 0; kt < 16; ++kt) {
    const int cur = kt & 1;
    __syncthreads();
    const s8v a = *(const s8v*)&lA[cur][arow * 40 + k8];
    if (kt < 15) *(s4v*)&lA[cur ^ 1][srow * 40 + sq4] = *(const s4v*)(aptr + ((kt + 1) << 5));
#pragma unroll
    for (int ni = 0; ni < 16; ++ni) {
      const int ntile = (slab << 5) + ((ni >> 3) << 4) + (wn << 3) + (ni & 7);
      const s8v* bp = (const s8v*)(W1 + ((((size_t)ntile << 4) + kt) * 64 + lane) * 8);
      ac[ni] = MFMA(a, *bp, ac[ni]);
    }
  }
#pragma unroll
  for (int ni = 0; ni < 16; ++ni) {
    const int col = (slab << 9) + (((((ni >> 3) << 4) + (wn << 3) + (ni & 7))) << 4) + (lane & 15);
#pragma unroll
    for (int q = 0; q < 4; q++) {
      const int row = (wm << 4) + ((lane >> 4) << 2) + q;
      XP[(size_t)(m0 + row) * 1536 + col] = f2bf(ac[ni][q]);
    }
  }
}

// ---------------- per-round kernel ----------------
struct RP {
  const int* sched;
  const int* preds;
  const int* edge_src;
  const float* ur_b;
  const float* wz_b;
  const float* wh_b;
  const unsigned short* XP;
  const unsigned short* WZB;
  const unsigned short* WHB;
  const unsigned short* WUR;
  unsigned short* A2h;
  unsigned short* A2g;
  unsigned short* u_bf;
  float* h;
  int B, Epc, P, E;
};

__global__ __launch_bounds__(256) void round_kernel(RP p, int r) {
  const int cnt = p.sched[1 + r];
  if (cnt == 0) return;
  const int M = cnt * p.B;
  const int nStripes = M >> 5;
  const int* lst = p.sched + 33 + r * 32;
  __shared__ unsigned short lAh[2][32 * 40];
  __shared__ unsigned short lAg[2][32 * 40];
  __shared__ unsigned short hL[32 * 520];
  __shared__ int eL[32];
  __shared__ int sL[32];
  const int tid = threadIdx.x, lane = tid & 63, w = tid >> 6;
  const int wm = w & 1, wn = w >> 1;
  const int srow = tid >> 3, sq4 = (tid & 7) << 2;
  const int arow = (wm << 4) | (lane & 15), k8 = (lane >> 4) << 3;

  for (int s = blockIdx.x; s < nStripes; s += gridDim.x) {
    const int m0 = s << 5;
    // ---- phase A: per-row pred gather; wave w owns rows w*8..w*8+8
    for (int ri = 0; ri < 8; ++ri) {
      const int lrow = (w << 3) + ri;
      const int m = m0 + lrow;
      const int j = m / p.B;
      const int b = m - j * p.B;
      const int e = b * p.Epc + lst[j];
      const int src = p.edge_src[e];
      if (lane == 0) { eL[lrow] = e; sL[lrow] = src; }
      const int c0 = lane << 3;
      const s8v xr8 = *(const s8v*)&p.XP[(size_t)src * 1536 + c0];
      float xb[8], ub[8], sh[8], sg[8];
#pragma unroll
      for (int i = 0; i < 8; i++) {
        xb[i] = bf2f((unsigned short)xr8[i]);
        ub[i] = p.ur_b[c0 + i];
        sh[i] = 0.f; sg[i] = 0.f;
      }
      for (int t = 0; t < p.P; ++t) {
        const int pe = p.preds[(size_t)e * p.P + t];
        if (pe >= p.E) continue;
        const float4* hp = (const float4*)(p.h + (size_t)pe * 512 + c0);
        const float4 h0 = hp[0], h1 = hp[1];
        const s8v u8 = *(const s8v*)&p.u_bf[(size_t)pe * 512 + c0];
        const float hv[8] = {h0.x, h0.y, h0.z, h0.w, h1.x, h1.y, h1.z, h1.w};
#pragma unroll
        for (int i = 0; i < 8; i++) {
          const float rr = 1.f / (1.f + __expf(-(xb[i] + bf2f((unsigned short)u8[i]) + ub[i])));
          sh[i] += hv[i];
          sg[i] += rr * hv[i];
        }
      }
      *(float4*)(p.h + (size_t)e * 512 + c0) = make_float4(sh[0], sh[1], sh[2], sh[3]);
      *(float4*)(p.h + (size_t)e * 512 + c0 + 4) = make_float4(sh[4], sh[5], sh[6], sh[7]);
      s8v shb, sgb;
#pragma unroll
      for (int i = 0; i < 8; i++) { shb[i] = (short)f2bf(sh[i]); sgb[i] = (short)f2bf(sg[i]); }
      *(s8v*)&p.A2h[(size_t)m * 512 + c0] = shb;
      *(s8v*)&p.A2g[(size_t)m * 512 + c0] = sgb;
    }
    __syncthreads();
    // ---- phase B: dual K=512 GEMM (sumh@WZB, sumg@WHB), dbuf staging, 1 sync/kt
    fx4 aZ[16], aH[16];
#pragma unroll
    for (int i = 0; i < 16; i++) {
      aZ[i][0]=0.f; aZ[i][1]=0.f; aZ[i][2]=0.f; aZ[i][3]=0.f;
      aH[i][0]=0.f; aH[i][1]=0.f; aH[i][2]=0.f; aH[i][3]=0.f;
    }
    const unsigned short* hrow = p.A2h + (size_t)(m0 + srow) * 512 + sq4;
    const unsigned short* grow = p.A2g + (size_t)(m0 + srow) * 512 + sq4;
    *(s4v*)&lAh[0][srow * 40 + sq4] = *(const s4v*)hrow;
    *(s4v*)&lAg[0][srow * 40 + sq4] = *(const s4v*)grow;
    for (int kt = 0; kt < 16; ++kt) {
      const int cur = kt & 1;
      __syncthreads();
      const s8v a1 = *(const s8v*)&lAh[cur][arow * 40 + k8];
      const s8v a2 = *(const s8v*)&lAg[cur][arow * 40 + k8];
      if (kt < 15) {
        *(s4v*)&lAh[cur ^ 1][srow * 40 + sq4] = *(const s4v*)(hrow + ((kt + 1) << 5));
        *(s4v*)&lAg[cur ^ 1][srow * 40 + sq4] = *(const s4v*)(grow + ((kt + 1) << 5));
      }
#pragma unroll
      for (int ni = 0; ni < 16; ++ni) {
        const int ntile = ((ni >> 3) << 4) + (wn << 3) + (ni & 7);
        const size_t boff = ((((size_t)ntile << 4) + kt) * 64 + lane) << 3;
        aZ[ni] = MFMA(a1, *(const s8v*)(p.WZB + boff), aZ[ni]);
        aH[ni] = MFMA(a2, *(const s8v*)(p.WHB + boff), aH[ni]);
      }
    }
    // ---- epilogue: gates + blend; write f32 h (global) + bf16 h (LDS)
#pragma unroll
    for (int q = 0; q < 4; ++q) {
      const int row = (wm << 4) + ((lane >> 4) << 2) + q;
      const int e = eL[row];
      const int src = sL[row];
#pragma unroll
      for (int ni = 0; ni < 16; ++ni) {
        const int col = (((((ni >> 3) << 4) + (wn << 3) + (ni & 7))) << 4) + (lane & 15);
        const size_t off = (size_t)e * 512 + col;
        float zpre = aZ[ni][q] + bf2f(p.XP[(size_t)src * 1536 + 512 + col]) + p.wz_b[col];
        float hpre = aH[ni][q] + bf2f(p.XP[(size_t)src * 1536 + 1024 + col]) + p.wh_b[col];
        float zz = 1.f / (1.f + __expf(-zpre));
        float e2 = __expf(2.f * hpre);
        float th = 1.f - 2.f / (e2 + 1.f);
        float hn = (1.f - zz) * p.h[off] + zz * th;
        p.h[off] = hn;
        hL[row * 520 + col] = f2bf(hn);
      }
    }
    __syncthreads();
    // ---- phase C: u = h @ WUR, A-frags straight from LDS, sync-free inner loop
    fx4 aU[16];
#pragma unroll
    for (int i = 0; i < 16; i++) { aU[i][0]=0.f; aU[i][1]=0.f; aU[i][2]=0.f; aU[i][3]=0.f; }
    for (int kt = 0; kt < 16; ++kt) {
      const s8v a = *(const s8v*)&hL[arow * 520 + (kt << 5) + k8];
#pragma unroll
      for (int ni = 0; ni < 16; ++ni) {
        const int ntile = ((ni >> 3) << 4) + (wn << 3) + (ni & 7);
        const size_t boff = ((((size_t)ntile << 4) + kt) * 64 + lane) << 3;
        aU[ni] = MFMA(a, *(const s8v*)(p.WUR + boff), aU[ni]);
      }
    }
#pragma unroll
    for (int q = 0; q < 4; ++q) {
      const int row = (wm << 4) + ((lane >> 4) << 2) + q;
      const int e = eL[row];
#pragma unroll
      for (int ni = 0; ni < 16; ++ni) {
        const int col = (((((ni >> 3) << 4) + (wn << 3) + (ni & 7))) << 4) + (lane & 15);
        p.u_bf[(size_t)e * 512 + col] = f2bf(aU[ni][q]);
      }
    }
    __syncthreads();
  }
}

// ---------------- root ----------------
__global__ void root_gather_kernel(const int* root_nodes, const int* root_in,
                                   const unsigned short* x_bf, const float* h,
                                   unsigned short* Aroot, int B, int R0) {
  int lane = threadIdx.x & 63;
  int waveId = blockIdx.x * (blockDim.x >> 6) + (threadIdx.x >> 6);
  int totalWaves = gridDim.x * (blockDim.x >> 6);
  for (int b = waveId; b < B; b += totalWaves) {
    int c0 = lane << 3;
    int nd = root_nodes[b];
    *(s8v*)&Aroot[(size_t)b * 1024 + c0] = *(const s8v*)&x_bf[(size_t)nd * HD + c0];
    float s[8];
#pragma unroll
    for (int i = 0; i < 8; i++) s[i] = 0.f;
    for (int t = 0; t < R0; ++t) {
      int e = root_in[b * R0 + t];
      const float4* hp = (const float4*)(h + (size_t)e * HD + c0);
      float4 h0 = hp[0], h1 = hp[1];
      s[0] += h0.x; s[1] += h0.y; s[2] += h0.z; s[3] += h0.w;
      s[4] += h1.x; s[5] += h1.y; s[6] += h1.z; s[7] += h1.w;
    }
    s8v sb;
#pragma unroll
    for (int i = 0; i < 8; i++) sb[i] = (short)f2bf(s[i]);
    *(s8v*)&Aroot[(size_t)b * 1024 + 512 + c0] = sb;
  }
}

__global__ __launch_bounds__(256) void gemm_root_kernel(const unsigned short* Aroot,
                                                        const unsigned short* WO,
                                                        const float* wo_b, float* out, int B) {
  __shared__ unsigned short lA[32 * 40];
  int tid = threadIdx.x, lane = tid & 63, w = tid >> 6;
  int wm = w & 1, wn = w >> 1;
  int bt = blockIdx.x;
  int mt = bt >> 1, nt = bt & 1;
  int m0 = mt << 5;
  fx4 ac[8];
#pragma unroll
  for (int n = 0; n < 8; n++) { ac[n][0]=0.f; ac[n][1]=0.f; ac[n][2]=0.f; ac[n][3]=0.f; }
  int srow = tid >> 3, squad = tid & 7;
  int arow = (wm << 4) | (lane & 15), k8 = (lane >> 4) << 3;
  for (int kt = 0; kt < 32; ++kt) {
    const unsigned short* g = Aroot + (size_t)(m0 + srow) * 1024 + (kt << 5) + (squad << 2);
    *(s4v*)&lA[srow * 40 + (squad << 2)] = *(const s4v*)g;
    __syncthreads();
    s8v a = *(const s8v*)&lA[arow * 40 + k8];
#pragma unroll
    for (int n = 0; n < 8; n++) {
      int ntile = (nt << 4) + (wn << 3) + n;
      size_t boff = ((((size_t)ntile * 32) + kt) * 64 + lane) << 3;
      ac[n] = MFMA(a, *(const s8v*)(WO + boff), ac[n]);
    }
    __syncthreads();
  }
#pragma unroll
  for (int q = 0; q < 4; q++) {
    int row = (wm << 4) + ((lane >> 4) << 2) + q;
    int m = m0 + row;
#pragma unroll
    for (int n = 0; n < 8; n++) {
      int col = (nt << 8) + (wn << 7) + (n << 4) + (lane & 15);
      float v = ac[n][q] + wo_b[col];
      out[(size_t)m * HD + col] = v > 0.f ? v : 0.f;
    }
  }
}

extern "C" void kernel_launch(void* const* d_in, const int* in_sizes, int n_in,
                              void* d_out, int out_size, void* d_ws, size_t ws_size,
                              hipStream_t stream) {
  const int* wid = (const int*)d_in[0];
  const int* edge_src = (const int*)d_in[1];
  const int* preds = (const int*)d_in[2];
  const int* root_in = (const int*)d_in[4];
  const int* root_nodes = (const int*)d_in[5];
  const float* emb = (const float*)d_in[6];
  const float* w_r = (const float*)d_in[7];
  const float* ur_w = (const float*)d_in[8];
  const float* ur_b = (const float*)d_in[9];
  const float* wz_w = (const float*)d_in[10];
  const float* wz_b = (const float*)d_in[11];
  const float* wh_w = (const float*)d_in[12];
  const float* wh_b = (const float*)d_in[13];
  const float* wo_w = (const float*)d_in[14];
  const float* wo_b = (const float*)d_in[15];

  const int BN = in_sizes[0];
  const int E = in_sizes[1];
  const int Bt = in_sizes[5];
  const int Epc = E / Bt;
  const int P = in_sizes[2] / (E + 1);
  const int R0 = in_sizes[4] / Bt;

  float* h = (float*)d_out;

  char* wp = (char*)d_ws;
  auto alloc = [&](size_t bytes) {
    char* r = wp;
    wp += (bytes + 255) & ~(size_t)255;
    return r;
  };
  unsigned short* x_bf = (unsigned short*)alloc((size_t)BN * 512 * 2);
  unsigned short* XP = (unsigned short*)alloc((size_t)BN * 1536 * 2);
  unsigned short* u_bf = (unsigned short*)alloc((size_t)E * 512 * 2);
  unsigned short* A2h = (unsigned short*)alloc((size_t)E * 512 * 2);
  unsigned short* A2g = (unsigned short*)alloc((size_t)E * 512 * 2);
  unsigned short* W1 = (unsigned short*)alloc((size_t)512 * 1536 * 2);
  unsigned short* WZB = (unsigned short*)alloc((size_t)512 * 512 * 2);
  unsigned short* WHB = (unsigned short*)alloc((size_t)512 * 512 * 2);
  unsigned short* WUR = (unsigned short*)alloc((size_t)512 * 512 * 2);
  unsigned short* WO = (unsigned short*)alloc((size_t)1024 * 512 * 2);
  unsigned short* Aroot = (unsigned short*)alloc((size_t)Bt * 1024 * 2);
  int* sched = (int*)alloc(8192);

  hipLaunchKernelGGL(pack_kernel, dim3(512), dim3(256), 0, stream,
                     w_r, ur_w, wz_w, wh_w, wo_w, W1, WZB, WHB, WUR, WO);
  hipLaunchKernelGGL(embed_kernel, dim3(1024), dim3(256), 0, stream, wid, emb, x_bf, BN);
  hipLaunchKernelGGL(schedule_kernel, dim3(1), dim3(64), 0, stream, preds, E, Epc, P, sched);
  hipLaunchKernelGGL(gemm_pre_kernel, dim3((BN / 32) * 3), dim3(256), 0, stream,
                     x_bf, W1, XP, BN);

  RP rp;
  rp.sched = sched;
  rp.preds = preds; rp.edge_src = edge_src;
  rp.ur_b = ur_b; rp.wz_b = wz_b; rp.wh_b = wh_b;
  rp.XP = XP;
  rp.WZB = WZB; rp.WHB = WHB; rp.WUR = WUR;
  rp.A2h = A2h; rp.A2g = A2g;
  rp.u_bf = u_bf;
  rp.h = h;
  rp.B = Bt; rp.Epc = Epc; rp.P = P; rp.E = E;

  for (int r = 0; r < Epc && r < 31; ++r) {
    hipLaunchKernelGGL(round_kernel, dim3(1024), dim3(256), 0, stream, rp, r);
  }

  hipLaunchKernelGGL(root_gather_kernel, dim3(512), dim3(256), 0, stream,
                     root_nodes, root_in, x_bf, h, Aroot, Bt, R0);
  hipLaunchKernelGGL(gemm_root_kernel, dim3((Bt / 32) * 2), dim3(256), 0, stream,
                     Aroot, WO, wo_b, h + (size_t)E * 512, Bt);
}

// Round 5
// 1127.293 us; speedup vs baseline: 2.0779x; 2.0779x over previous
//
#include <hip/hip_runtime.h>
#include <hip/hip_bf16.h>
#include <cstddef>

#define HD 512

typedef short s8v __attribute__((ext_vector_type(8)));
typedef short s4v __attribute__((ext_vector_type(4)));
typedef float fx4 __attribute__((ext_vector_type(4)));

#define MFMA(a, b, c) __builtin_amdgcn_mfma_f32_16x16x32_bf16((a), (b), (c), 0, 0, 0)

__device__ __forceinline__ unsigned short f2bf(float f) {
  unsigned int u = __float_as_uint(f);
  unsigned int r = (u + 0x7fffu + ((u >> 16) & 1u)) >> 16;
  return (unsigned short)r;
}
__device__ __forceinline__ float bf2f(unsigned short u) {
  return __uint_as_float(((unsigned int)u) << 16);
}

// Swizzled B-operand layout for 16x16x32 MFMA (R1/R3-proven):
// element (k,n) -> chunk (ntile*KT + kt); lane = ((k&31)>>3)<<4 | (n&15); i = k&7
__device__ __forceinline__ size_t swz_off(int k, int n, int KT) {
  int kt = k >> 5, kr = k & 31;
  int nt = n >> 4, nr = n & 15;
  int lane = ((kr >> 3) << 4) | nr;
  int i = kr & 7;
  return ((((size_t)nt * KT + kt) * 64 + lane) << 3) + i;
}

// ---------------- pack weights ----------------
// WR/WUR: 512x512 KT=16.  WZf/WHf/WO: 1024x512 KT=32 (full K incl. x-half).
__global__ void pack_kernel(const float* w_r, const float* ur, const float* wz, const float* wh,
                            const float* wo,
                            unsigned short* WR, unsigned short* WUR, unsigned short* WZf,
                            unsigned short* WHf, unsigned short* WO) {
  int idx = blockIdx.x * blockDim.x + threadIdx.x;
  int stride = gridDim.x * blockDim.x;
  for (int t = idx; t < 512 * 512; t += stride) {
    int k = t >> 9, n = t & 511;
    size_t o = swz_off(k, n, 16);
    WR[o] = f2bf(w_r[t]);
    WUR[o] = f2bf(ur[t]);
  }
  for (int t = idx; t < 1024 * 512; t += stride) {
    int k = t >> 9, n = t & 511;
    size_t o = swz_off(k, n, 32);
    WZf[o] = f2bf(wz[t]);
    WHf[o] = f2bf(wh[t]);
    WO[o] = f2bf(wo[t]);
  }
}

// ---------------- embedding gather ----------------
__global__ void embed_kernel(const int* wid, const float* emb, unsigned short* x_bf, int BN) {
  int idx = blockIdx.x * blockDim.x + threadIdx.x;
  int stride = gridDim.x * blockDim.x;
  int total = BN * (HD / 8);
  for (int t = idx; t < total; t += stride) {
    int nrow = t >> 6;
    int c8 = (t & 63) << 3;
    int w = wid[nrow];
    const float4* s = (const float4*)(emb + (size_t)w * HD + c8);
    float4 v0 = s[0], v1 = s[1];
    s8v o;
    o[0] = (short)f2bf(v0.x); o[1] = (short)f2bf(v0.y);
    o[2] = (short)f2bf(v0.z); o[3] = (short)f2bf(v0.w);
    o[4] = (short)f2bf(v1.x); o[5] = (short)f2bf(v1.y);
    o[6] = (short)f2bf(v1.z); o[7] = (short)f2bf(v1.w);
    *(s8v*)&x_bf[(size_t)nrow * HD + c8] = o;
  }
}

// ---------------- schedule ----------------
__global__ void schedule_kernel(const int* preds, int E, int Epc, int P, int* sched) {
  __shared__ int rnd[64];
  int t = threadIdx.x;
  rnd[t] = -1;
  __syncthreads();
  for (int it = 0; it <= Epc; ++it) {
    int newv = -1;
    if (t < Epc && rnd[t] < 0) {
      int mx = 0;
      bool ready = true;
      for (int q = 0; q < P; ++q) {
        int pe = preds[t * P + q];
        if (pe < E) {
          int rp = rnd[pe];
          if (rp < 0) ready = false;
          else if (rp + 1 > mx) mx = rp + 1;
        }
      }
      if (ready) newv = mx;
    }
    __syncthreads();
    if (newv >= 0) rnd[t] = newv;
    __syncthreads();
  }
  if (t == 0) {
    int R = 0;
    for (int e = 0; e < Epc; ++e) if (rnd[e] + 1 > R) R = rnd[e] + 1;
    if (R > 31) R = 31;
    sched[0] = R;
    for (int r = 0; r < 31; ++r) {
      int c = 0;
      if (r < R) {
        for (int e = 0; e < Epc; ++e) if (rnd[e] == r) { sched[33 + r * 32 + c] = e; ++c; }
      }
      sched[1 + r] = c;
    }
  }
}

// ---------------- XR = x_bf @ w_r (R3-proven) ----------------
__global__ __launch_bounds__(256) void gemm_xr_kernel(const unsigned short* x_bf,
                                                      const unsigned short* WR,
                                                      unsigned short* XR, int BN) {
  __shared__ unsigned short lA[32 * 40];
  int bt = blockIdx.x;
  int mt = bt >> 1, nt = bt & 1;
  int tid = threadIdx.x, lane = tid & 63, w = tid >> 6;
  int wm = w & 1, wn = w >> 1;
  int m0 = mt << 5;
  fx4 acc[8];
#pragma unroll
  for (int n = 0; n < 8; n++) { acc[n][0]=0.f; acc[n][1]=0.f; acc[n][2]=0.f; acc[n][3]=0.f; }
  int srow = tid >> 3, squad = tid & 7;
  int arow = (wm << 4) | (lane & 15), k8 = (lane >> 4) << 3;
  for (int kt = 0; kt < 16; ++kt) {
    const unsigned short* gp = x_bf + (size_t)(m0 + srow) * HD + (kt << 5) + (squad << 2);
    *(s4v*)&lA[srow * 40 + (squad << 2)] = *(const s4v*)gp;
    __syncthreads();
    s8v a = *(const s8v*)&lA[arow * 40 + k8];
#pragma unroll
    for (int n = 0; n < 8; n++) {
      int ntile = (nt << 4) + (wn << 3) + n;
      const s8v* bp = (const s8v*)(WR + ((((size_t)ntile << 4) + kt) * 64 + lane) * 8);
      acc[n] = MFMA(a, *bp, acc[n]);
    }
    __syncthreads();
  }
#pragma unroll
  for (int n = 0; n < 8; n++) {
    int gcol = (nt << 8) + (wn << 7) + (n << 4) + (lane & 15);
#pragma unroll
    for (int q = 0; q < 4; q++) {
      int row = (wm << 4) + ((lane >> 4) << 2) + q;
      XR[(size_t)(m0 + row) * 512 + gcol] = f2bf(acc[n][q]);
    }
  }
}

// ---------------- phase A: gather kernel (high occupancy, no LDS) ----------------
struct AP {
  const int* sched;
  const int* preds;
  const int* edge_src;
  const float* ur_b;
  const unsigned short* XR;
  const unsigned short* u_bf_c;
  unsigned short* A2h;
  unsigned short* A2g;
  int* eIdx;
  int* srcIdx;
  float* h;
  int B, Epc, P, E;
};

__global__ __launch_bounds__(256) void gatherA_kernel(AP p, int r) {
  const int cnt = p.sched[1 + r];
  if (cnt == 0) return;
  const int M = cnt * p.B;
  const int* lst = p.sched + 33 + r * 32;
  const int lane = threadIdx.x & 63;
  const int waveId = blockIdx.x * 4 + (threadIdx.x >> 6);
  const int totalWaves = gridDim.x * 4;
  for (int m = waveId; m < M; m += totalWaves) {
    const int j = m / p.B;
    const int b = m - j * p.B;
    const int e = b * p.Epc + lst[j];
    const int src = p.edge_src[e];
    if (lane == 0) { p.eIdx[m] = e; p.srcIdx[m] = src; }
    const int c0 = lane << 3;
    const s8v xr8 = *(const s8v*)&p.XR[(size_t)src * 512 + c0];
    float xb[8], ub[8], sh[8], sg[8];
#pragma unroll
    for (int i = 0; i < 8; i++) {
      xb[i] = bf2f((unsigned short)xr8[i]);
      ub[i] = p.ur_b[c0 + i];
      sh[i] = 0.f; sg[i] = 0.f;
    }
    for (int t = 0; t < p.P; ++t) {
      const int pe = p.preds[(size_t)e * p.P + t];
      if (pe >= p.E) continue;
      const float4* hp = (const float4*)(p.h + (size_t)pe * 512 + c0);
      const float4 h0 = hp[0], h1 = hp[1];
      const s8v u8 = *(const s8v*)&p.u_bf_c[(size_t)pe * 512 + c0];
      const float hv[8] = {h0.x, h0.y, h0.z, h0.w, h1.x, h1.y, h1.z, h1.w};
#pragma unroll
      for (int i = 0; i < 8; i++) {
        const float rr = 1.f / (1.f + __expf(-(xb[i] + bf2f((unsigned short)u8[i]) + ub[i])));
        sh[i] += hv[i];
        sg[i] += rr * hv[i];
      }
    }
    *(float4*)(p.h + (size_t)e * 512 + c0) = make_float4(sh[0], sh[1], sh[2], sh[3]);
    *(float4*)(p.h + (size_t)e * 512 + c0 + 4) = make_float4(sh[4], sh[5], sh[6], sh[7]);
    s8v shb, sgb;
#pragma unroll
    for (int i = 0; i < 8; i++) { shb[i] = (short)f2bf(sh[i]); sgb[i] = (short)f2bf(sg[i]); }
    *(s8v*)&p.A2h[(size_t)m * 512 + c0] = shb;
    *(s8v*)&p.A2g[(size_t)m * 512 + c0] = sgb;
  }
}

// ---------------- phase B: dual z/h GEMM (K=1024) + gate epilogue ----------------
// 64-row x 128-col tiles; dbuf LDS A-staging, 1 sync/kt; waves 2x2 (32rx64c each).
struct BP {
  const int* sched;
  const float* wz_b;
  const float* wh_b;
  const unsigned short* x_bf;
  const unsigned short* A2h;
  const unsigned short* A2g;
  const unsigned short* WZf;
  const unsigned short* WHf;
  const int* eIdx;
  const int* srcIdx;
  unsigned short* h_bf;
  float* h;
  int B;
};

__global__ __launch_bounds__(256) void gemmB_kernel(BP p, int r) {
  const int cnt = p.sched[1 + r];
  if (cnt == 0) return;
  const int M = cnt * p.B;
  const int nTiles = (M >> 6) << 2;
  __shared__ unsigned short lZ[2][64 * 40];
  __shared__ unsigned short lH[2][64 * 40];
  __shared__ int eL[64];
  __shared__ int sL[64];
  const int tid = threadIdx.x, lane = tid & 63, w = tid >> 6;
  const int wm = w & 1, wn = w >> 1;
  const int srow = tid >> 2, sc8 = (tid & 3) << 3;
  const int k8 = (lane >> 4) << 3;

  for (int t = blockIdx.x; t < nTiles; t += gridDim.x) {
    const int mt = t >> 2, nb = t & 3;
    const int m0 = mt << 6, n0 = nb << 7;
    if (tid < 64) { eL[tid] = p.eIdx[m0 + tid]; sL[tid] = p.srcIdx[m0 + tid]; }
    __syncthreads();
    fx4 aZ[8], aH[8];
#pragma unroll
    for (int i = 0; i < 8; i++) {
      aZ[i][0]=0.f; aZ[i][1]=0.f; aZ[i][2]=0.f; aZ[i][3]=0.f;
      aH[i][0]=0.f; aH[i][1]=0.f; aH[i][2]=0.f; aH[i][3]=0.f;
    }
    // prologue: stage kt=0 (x half; z and h share it)
    {
      const unsigned short* g = p.x_bf + (size_t)sL[srow] * 512 + sc8;
      *(s8v*)&lZ[0][srow * 40 + sc8] = *(const s8v*)g;
    }
    for (int kt = 0; kt < 32; ++kt) {
      const int cur = kt & 1;
      __syncthreads();
      if (kt < 31) {
        const int k2 = kt + 1;
        if (k2 < 16) {
          const unsigned short* g = p.x_bf + (size_t)sL[srow] * 512 + (k2 << 5) + sc8;
          *(s8v*)&lZ[cur ^ 1][srow * 40 + sc8] = *(const s8v*)g;
        } else {
          const size_t ro = (size_t)(m0 + srow) * 512 + ((k2 - 16) << 5) + sc8;
          *(s8v*)&lZ[cur ^ 1][srow * 40 + sc8] = *(const s8v*)&p.A2h[ro];
          *(s8v*)&lH[cur ^ 1][srow * 40 + sc8] = *(const s8v*)&p.A2g[ro];
        }
      }
      s8v az[2], ah[2];
#pragma unroll
      for (int mi = 0; mi < 2; ++mi) {
        const int ao = ((wm << 5) + (mi << 4) + (lane & 15)) * 40 + k8;
        az[mi] = *(const s8v*)&lZ[cur][ao];
        ah[mi] = (kt < 16) ? az[mi] : *(const s8v*)&lH[cur][ao];
      }
#pragma unroll
      for (int ni = 0; ni < 4; ++ni) {
        const int ntile = (n0 >> 4) + (wn << 2) + ni;
        const size_t boff = (((size_t)ntile * 32 + kt) * 64 + lane) << 3;
        const s8v bz = *(const s8v*)(p.WZf + boff);
        const s8v bh = *(const s8v*)(p.WHf + boff);
#pragma unroll
        for (int mi = 0; mi < 2; ++mi) {
          aZ[mi * 4 + ni] = MFMA(az[mi], bz, aZ[mi * 4 + ni]);
          aH[mi * 4 + ni] = MFMA(ah[mi], bh, aH[mi * 4 + ni]);
        }
      }
    }
    // epilogue: gates + blend
#pragma unroll
    for (int mi = 0; mi < 2; ++mi) {
#pragma unroll
      for (int q = 0; q < 4; ++q) {
        const int row = (wm << 5) + (mi << 4) + ((lane >> 4) << 2) + q;
        const int e = eL[row];
#pragma unroll
        for (int ni = 0; ni < 4; ++ni) {
          const int col = n0 + (wn << 6) + (ni << 4) + (lane & 15);
          const size_t off = (size_t)e * 512 + col;
          float zpre = aZ[mi * 4 + ni][q] + p.wz_b[col];
          float hpre = aH[mi * 4 + ni][q] + p.wh_b[col];
          float zz = 1.f / (1.f + __expf(-zpre));
          float e2 = __expf(2.f * hpre);
          float th = 1.f - 2.f / (e2 + 1.f);
          float hn = (1.f - zz) * p.h[off] + zz * th;
          p.h[off] = hn;
          p.h_bf[off] = f2bf(hn);
        }
      }
    }
    __syncthreads();
  }
}

// ---------------- phase C: u = h_bf @ WUR (K=512), 64x128 tiles ----------------
struct CP {
  const int* sched;
  const unsigned short* h_bf;
  const unsigned short* WUR;
  const int* eIdx;
  unsigned short* u_bf;
  int B;
};

__global__ __launch_bounds__(256) void gemmC_kernel(CP p, int r) {
  const int cnt = p.sched[1 + r];
  if (cnt == 0) return;
  const int M = cnt * p.B;
  const int nTiles = (M >> 6) << 2;
  __shared__ unsigned short lA[2][64 * 40];
  __shared__ int eL[64];
  const int tid = threadIdx.x, lane = tid & 63, w = tid >> 6;
  const int wm = w & 1, wn = w >> 1;
  const int srow = tid >> 2, sc8 = (tid & 3) << 3;
  const int k8 = (lane >> 4) << 3;

  for (int t = blockIdx.x; t < nTiles; t += gridDim.x) {
    const int mt = t >> 2, nb = t & 3;
    const int m0 = mt << 6, n0 = nb << 7;
    if (tid < 64) eL[tid] = p.eIdx[m0 + tid];
    __syncthreads();
    fx4 ac[8];
#pragma unroll
    for (int i = 0; i < 8; i++) { ac[i][0]=0.f; ac[i][1]=0.f; ac[i][2]=0.f; ac[i][3]=0.f; }
    {
      const unsigned short* g = p.h_bf + (size_t)eL[srow] * 512 + sc8;
      *(s8v*)&lA[0][srow * 40 + sc8] = *(const s8v*)g;
    }
    for (int kt = 0; kt < 16; ++kt) {
      const int cur = kt & 1;
      __syncthreads();
      if (kt < 15) {
        const unsigned short* g = p.h_bf + (size_t)eL[srow] * 512 + ((kt + 1) << 5) + sc8;
        *(s8v*)&lA[cur ^ 1][srow * 40 + sc8] = *(const s8v*)g;
      }
      s8v az[2];
#pragma unroll
      for (int mi = 0; mi < 2; ++mi) {
        az[mi] = *(const s8v*)&lA[cur][((wm << 5) + (mi << 4) + (lane & 15)) * 40 + k8];
      }
#pragma unroll
      for (int ni = 0; ni < 4; ++ni) {
        const int ntile = (n0 >> 4) + (wn << 2) + ni;
        const size_t boff = (((size_t)ntile << 4) + kt) * 64 + lane;
        const s8v bu = *(const s8v*)(p.WUR + (boff << 3));
#pragma unroll
        for (int mi = 0; mi < 2; ++mi) {
          ac[mi * 4 + ni] = MFMA(az[mi], bu, ac[mi * 4 + ni]);
        }
      }
    }
#pragma unroll
    for (int mi = 0; mi < 2; ++mi) {
#pragma unroll
      for (int q = 0; q < 4; ++q) {
        const int row = (wm << 5) + (mi << 4) + ((lane >> 4) << 2) + q;
        const int e = eL[row];
#pragma unroll
        for (int ni = 0; ni < 4; ++ni) {
          const int col = n0 + (wn << 6) + (ni << 4) + (lane & 15);
          p.u_bf[(size_t)e * 512 + col] = f2bf(ac[mi * 4 + ni][q]);
        }
      }
    }
    __syncthreads();
  }
}

// ---------------- root (R1/R3-proven) ----------------
__global__ void root_gather_kernel(const int* root_nodes, const int* root_in,
                                   const unsigned short* x_bf, const float* h,
                                   unsigned short* Aroot, int B, int R0) {
  int lane = threadIdx.x & 63;
  int waveId = blockIdx.x * (blockDim.x >> 6) + (threadIdx.x >> 6);
  int totalWaves = gridDim.x * (blockDim.x >> 6);
  for (int b = waveId; b < B; b += totalWaves) {
    int c0 = lane << 3;
    int nd = root_nodes[b];
    *(s8v*)&Aroot[(size_t)b * 1024 + c0] = *(const s8v*)&x_bf[(size_t)nd * HD + c0];
    float s[8];
#pragma unroll
    for (int i = 0; i < 8; i++) s[i] = 0.f;
    for (int t = 0; t < R0; ++t) {
      int e = root_in[b * R0 + t];
      const float4* hp = (const float4*)(h + (size_t)e * HD + c0);
      float4 h0 = hp[0], h1 = hp[1];
      s[0] += h0.x; s[1] += h0.y; s[2] += h0.z; s[3] += h0.w;
      s[4] += h1.x; s[5] += h1.y; s[6] += h1.z; s[7] += h1.w;
    }
    s8v sb;
#pragma unroll
    for (int i = 0; i < 8; i++) sb[i] = (short)f2bf(s[i]);
    *(s8v*)&Aroot[(size_t)b * 1024 + 512 + c0] = sb;
  }
}

__global__ __launch_bounds__(256) void gemm_root_kernel(const unsigned short* Aroot,
                                                        const unsigned short* WO,
                                                        const float* wo_b, float* out, int B) {
  __shared__ unsigned short lA[32 * 40];
  int tid = threadIdx.x, lane = tid & 63, w = tid >> 6;
  int wm = w & 1, wn = w >> 1;
  int bt = blockIdx.x;
  int mt = bt >> 1, nt = bt & 1;
  int m0 = mt << 5;
  fx4 ac[8];
#pragma unroll
  for (int n = 0; n < 8; n++) { ac[n][0]=0.f; ac[n][1]=0.f; ac[n][2]=0.f; ac[n][3]=0.f; }
  int srow = tid >> 3, squad = tid & 7;
  int arow = (wm << 4) | (lane & 15), k8 = (lane >> 4) << 3;
  for (int kt = 0; kt < 32; ++kt) {
    const unsigned short* g = Aroot + (size_t)(m0 + srow) * 1024 + (kt << 5) + (squad << 2);
    *(s4v*)&lA[srow * 40 + (squad << 2)] = *(const s4v*)g;
    __syncthreads();
    s8v a = *(const s8v*)&lA[arow * 40 + k8];
#pragma unroll
    for (int n = 0; n < 8; n++) {
      int ntile = (nt << 4) + (wn << 3) + n;
      size_t boff = ((((size_t)ntile * 32) + kt) * 64 + lane) << 3;
      ac[n] = MFMA(a, *(const s8v*)(WO + boff), ac[n]);
    }
    __syncthreads();
  }
#pragma unroll
  for (int q = 0; q < 4; q++) {
    int row = (wm << 4) + ((lane >> 4) << 2) + q;
    int m = m0 + row;
#pragma unroll
    for (int n = 0; n < 8; n++) {
      int col = (nt << 8) + (wn << 7) + (n << 4) + (lane & 15);
      float v = ac[n][q] + wo_b[col];
      out[(size_t)m * HD + col] = v > 0.f ? v : 0.f;
    }
  }
}

extern "C" void kernel_launch(void* const* d_in, const int* in_sizes, int n_in,
                              void* d_out, int out_size, void* d_ws, size_t ws_size,
                              hipStream_t stream) {
  const int* wid = (const int*)d_in[0];
  const int* edge_src = (const int*)d_in[1];
  const int* preds = (const int*)d_in[2];
  const int* root_in = (const int*)d_in[4];
  const int* root_nodes = (const int*)d_in[5];
  const float* emb = (const float*)d_in[6];
  const float* w_r = (const float*)d_in[7];
  const float* ur_w = (const float*)d_in[8];
  const float* ur_b = (const float*)d_in[9];
  const float* wz_w = (const float*)d_in[10];
  const float* wz_b = (const float*)d_in[11];
  const float* wh_w = (const float*)d_in[12];
  const float* wh_b = (const float*)d_in[13];
  const float* wo_w = (const float*)d_in[14];
  const float* wo_b = (const float*)d_in[15];

  const int BN = in_sizes[0];
  const int E = in_sizes[1];
  const int Bt = in_sizes[5];
  const int Epc = E / Bt;
  const int P = in_sizes[2] / (E + 1);
  const int R0 = in_sizes[4] / Bt;

  float* h = (float*)d_out;

  char* wp = (char*)d_ws;
  auto alloc = [&](size_t bytes) {
    char* r = wp;
    wp += (bytes + 255) & ~(size_t)255;
    return r;
  };
  unsigned short* x_bf = (unsigned short*)alloc((size_t)BN * 512 * 2);
  unsigned short* XR = (unsigned short*)alloc((size_t)BN * 512 * 2);
  unsigned short* h_bf = (unsigned short*)alloc((size_t)E * 512 * 2);
  unsigned short* u_bf = (unsigned short*)alloc((size_t)E * 512 * 2);
  unsigned short* A2h = (unsigned short*)alloc((size_t)E * 512 * 2);
  unsigned short* A2g = (unsigned short*)alloc((size_t)E * 512 * 2);
  int* eIdx = (int*)alloc((size_t)E * 4);
  int* srcIdx = (int*)alloc((size_t)E * 4);
  unsigned short* WR = (unsigned short*)alloc((size_t)512 * 512 * 2);
  unsigned short* WUR = (unsigned short*)alloc((size_t)512 * 512 * 2);
  unsigned short* WZf = (unsigned short*)alloc((size_t)1024 * 512 * 2);
  unsigned short* WHf = (unsigned short*)alloc((size_t)1024 * 512 * 2);
  unsigned short* WO = (unsigned short*)alloc((size_t)1024 * 512 * 2);
  unsigned short* Aroot = (unsigned short*)alloc((size_t)Bt * 1024 * 2);
  int* sched = (int*)alloc(8192);

  hipLaunchKernelGGL(pack_kernel, dim3(512), dim3(256), 0, stream,
                     w_r, ur_w, wz_w, wh_w, wo_w, WR, WUR, WZf, WHf, WO);
  hipLaunchKernelGGL(embed_kernel, dim3(1024), dim3(256), 0, stream, wid, emb, x_bf, BN);
  hipLaunchKernelGGL(schedule_kernel, dim3(1), dim3(64), 0, stream, preds, E, Epc, P, sched);
  hipLaunchKernelGGL(gemm_xr_kernel, dim3((BN / 32) * 2), dim3(256), 0, stream, x_bf, WR, XR, BN);

  AP ap;
  ap.sched = sched; ap.preds = preds; ap.edge_src = edge_src;
  ap.ur_b = ur_b; ap.XR = XR; ap.u_bf_c = u_bf;
  ap.A2h = A2h; ap.A2g = A2g; ap.eIdx = eIdx; ap.srcIdx = srcIdx;
  ap.h = h; ap.B = Bt; ap.Epc = Epc; ap.P = P; ap.E = E;

  BP bp;
  bp.sched = sched; bp.wz_b = wz_b; bp.wh_b = wh_b;
  bp.x_bf = x_bf; bp.A2h = A2h; bp.A2g = A2g;
  bp.WZf = WZf; bp.WHf = WHf;
  bp.eIdx = eIdx; bp.srcIdx = srcIdx;
  bp.h_bf = h_bf; bp.h = h; bp.B = Bt;

  CP cp;
  cp.sched = sched; cp.h_bf = h_bf; cp.WUR = WUR;
  cp.eIdx = eIdx; cp.u_bf = u_bf; cp.B = Bt;

  for (int r = 0; r < Epc && r < 31; ++r) {
    hipLaunchKernelGGL(gatherA_kernel, dim3(1024), dim3(256), 0, stream, ap, r);
    hipLaunchKernelGGL(gemmB_kernel, dim3(2048), dim3(256), 0, stream, bp, r);
    hipLaunchKernelGGL(gemmC_kernel, dim3(2048), dim3(256), 0, stream, cp, r);
  }

  hipLaunchKernelGGL(root_gather_kernel, dim3(512), dim3(256), 0, stream,
                     root_nodes, root_in, x_bf, h, Aroot, Bt, R0);
  hipLaunchKernelGGL(gemm_root_kernel, dim3((Bt / 32) * 2), dim3(256), 0, stream,
                     Aroot, WO, wo_b, h + (size_t)E * 512, Bt);
}